// Round 5
// baseline (181.668 us; speedup 1.0000x reference)
//
#include <hip/hip_runtime.h>

// TotalDegree: out[b, t] = prod over multiset term t of x[b, d]; 495 terms =
// multisets of size 0..4 over 8 vars, DFS-lex order (order verified in prior
// rounds, absmax 0.125 pass).
// R7 EXPERIMENT (single concept): fill-shaped write front. R2/R5/R6 (three
// different compute+store structures) all tie at ~50 us vs the 20 us write
// floor, while the harness fill sustains 6.5 TB/s on the same buffer. Shared
// trait: block b owns a contiguous 63-KB span and ALL 2048 blocks are resident
// -> in-flight stores are 2048 sparse streams over 124 MB -> DRAM row-buffer
// thrash. The fill instead sweeps one dense window. Fix: flat-tile out into
// 31680 4-KB units; block b does units b, b+2048, ... -> resident blocks form
// one contiguous ~8 MB band sweeping the buffer. Block-local P staging is
// impossible across 8-MB jumps, so compute goes LDS-free: each element is a
// masked product of <=4 x-values picked by a 2-KB constant desc table (L1-hot;
// x window per wave = <=2 rows = 64 B, L1-broadcast). Zero LDS, zero barriers
// -> also a clean probe: if this STILL ties ~50 us, the residual is fixed
// overhead and we are at the structural floor.

typedef float f32x4 __attribute__((ext_vector_type(4)));

struct DTbl { unsigned d[512]; };  // [t]: d0|d1<<3|d2<<6|d3<<9 | mask<<12

constexpr DTbl make_dtbl() {
    DTbl T{};
    int idx = 0;
    T.d[idx++] = 0u;  // empty term -> product of nothing = 1.0
    for (int a = 0; a < 8; ++a) {
        T.d[idx++] = (unsigned)a | (1u << 12);
        for (int b = a; b < 8; ++b) {
            T.d[idx++] = (unsigned)(a | (b << 3)) | (3u << 12);
            for (int c = b; c < 8; ++c) {
                T.d[idx++] = (unsigned)(a | (b << 3) | (c << 6)) | (7u << 12);
                for (int d = c; d < 8; ++d)
                    T.d[idx++] =
                        (unsigned)(a | (b << 3) | (c << 6) | (d << 9)) | (15u << 12);
            }
        }
    }  // idx == 495
    for (int j = 0; j < 17; ++j) T.d[495 + j] = T.d[j];  // wrap pad: t+3 <= 497
    return T;
}

__constant__ DTbl DT = make_dtbl();

#define NBLOCKS 2048

// One element: term desc q, row base pointer xb (8 floats). Loads are issued
// unconditionally (always in-bounds) then masked via select -> branchless.
__device__ __forceinline__ float term_val(const float* __restrict__ xb, unsigned q) {
    const float la = xb[q & 7u];
    const float lb = xb[(q >> 3) & 7u];
    const float lc = xb[(q >> 6) & 7u];
    const float ld = xb[(q >> 9) & 7u];
    const float a = (q & 0x1000u) ? la : 1.0f;
    const float b = (q & 0x2000u) ? lb : 1.0f;
    const float c = (q & 0x4000u) ? lc : 1.0f;
    const float d = (q & 0x8000u) ? ld : 1.0f;
    return (a * b) * (c * d);
}

__global__ __launch_bounds__(256, 8) void TotalDegree_29755533426739_kernel(
    const float* __restrict__ x, float* __restrict__ out, unsigned nunits) {
    const int tid = (int)threadIdx.x;

    unsigned u = blockIdx.x;                       // 4-KB unit index
    const unsigned f0 = u * 1024u + (unsigned)(tid << 2);  // flat word index, < 2^21
    unsigned r = f0 / 495u;                        // row   (exact div, once)
    unsigned t = f0 - r * 495u;                    // term

    while (u < nunits) {
        // 4 consecutive flat words: terms t..t+3, wrapping into row r+1 at 495.
        const unsigned q0 = DT.d[t];
        const unsigned q1 = DT.d[t + 1];
        const unsigned q2 = DT.d[t + 2];
        const unsigned q3 = DT.d[t + 3];
        const float* xb0 = x + (r << 3);
        const float* xb1 = x + ((r + (t >= 494u)) << 3);
        const float* xb2 = x + ((r + (t >= 493u)) << 3);
        const float* xb3 = x + ((r + (t >= 492u)) << 3);

        f32x4 v;
        v.x = term_val(xb0, q0);
        v.y = term_val(xb1, q1);
        v.z = term_val(xb2, q2);
        v.w = term_val(xb3, q3);

        // unit base byte = u*4096 (line-aligned); 4 wave-stores cover the unit,
        // every 128-B line written whole by exactly one store.
        *reinterpret_cast<f32x4*>(out + (size_t)u * 1024u + (unsigned)(tid << 2)) = v;

        // advance one block-stride: 2048 units = 2,097,152 words = 4236*495+332
        u += NBLOCKS;
        r += 4236u;
        t += 332u;
        if (t >= 495u) { t -= 495u; ++r; }
    }
}

extern "C" void kernel_launch(void* const* d_in, const int* in_sizes, int n_in,
                              void* d_out, int out_size, void* d_ws, size_t ws_size,
                              hipStream_t stream) {
    const float* x = (const float*)d_in[0];
    float* out = (float*)d_out;
    const int B = in_sizes[0] / 8;  // 65536 rows
    // total words = B*495; exact 1024-word units for B = 65536 (495*2^16/2^10).
    const unsigned nunits = (unsigned)(((long long)B * 495) / 1024);
    hipLaunchKernelGGL(TotalDegree_29755533426739_kernel,
                       dim3(NBLOCKS), dim3(256), 0, stream, x, out, nunits);
}

// Round 6
// 129.793 us; speedup vs baseline: 1.3997x; 1.3997x over previous
//
#include <hip/hip_runtime.h>

// TotalDegree: out[b, t] = prod over multiset term t of x[b, d]; 495 terms =
// multisets of size 0..4 over 8 vars, DFS-lex order. term = P[u]*P[v], P = 45
// multisets of size <= 2 (verified factorization).
// R8 = resubmission of R6 (session best, 129.8 us): R7's counters proved
// traffic is already ideal (WRITE_SIZE == output bytes, FETCH == x bytes) and
// that dur = fill(~78) + harness gap(~22) + kernel(~30); the kernel sits at
// the 130-MB write floor (~20 us) + launch/ramp (~8 us). R7's LDS-free variant
// was compute-bound (VALUBusy 36%, 16 scalar VMEM per 4 outputs) - reverted.
// Structure: P staged in LDS for all 32 block rows; block output span
// (63360 B = exactly 495 lines) tiled into 62 flat 1-KB units; every
// global_store_dwordx4 covers whole 128-B lines; term->(u,v) map read from a
// 4-way-interleaved LDS table (lanes' t stride-4 -> conflict-free).

typedef float f32x4 __attribute__((ext_vector_type(4)));

struct Tbl {
    unsigned uv4[512];       // [(t&3)*128 + (t>>2)] = u | v<<16, t in 0..498
    unsigned short pp[64];   // per lane: s1 | s2<<4 | use1<<8 | use2<<9
};

constexpr int pidx_c(int a, int b) {
    return 9 + 8 * a - (a * (a - 1)) / 2 + (b - a);  // empty=0, singles 1..8, pairs 9..44
}

constexpr Tbl make_tbl() {
    Tbl T{};
    unsigned lin[500] = {};
    int idx = 1;  // term 0 = empty -> u=v=0 -> P[0]*P[0] = 1
    for (int a = 0; a < 8; ++a) {
        lin[idx++] = (unsigned)(1 + a);
        for (int b = a; b < 8; ++b) {
            lin[idx++] = (unsigned)pidx_c(a, b);
            for (int c = b; c < 8; ++c) {
                lin[idx++] = (unsigned)pidx_c(a, b) | ((unsigned)(1 + c) << 16);
                for (int d = c; d < 8; ++d)
                    lin[idx++] = (unsigned)pidx_c(a, b) | ((unsigned)pidx_c(c, d) << 16);
            }
        }
    }  // idx == 495; pad so reads at t..t+3 (t<=494) stay valid, wrapped rows
    for (int i = 0; i < 5; ++i) lin[495 + i] = lin[i];
    for (int t = 0; t < 499; ++t) T.uv4[(t & 3) * 128 + (t >> 2)] = lin[t];
    for (int l = 0; l < 64; ++l) {
        int s1 = 0, s2 = 0, u1 = 0, u2 = 0;
        if (l >= 1 && l <= 8) { s1 = l - 1; u1 = 1; }
        else if (l >= 9 && l < 45) {
            int k = l - 9, i = 0;
            while (k >= 8 - i) { k -= 8 - i; ++i; }
            s1 = i; s2 = i + k; u1 = 1; u2 = 1;
        }
        T.pp[l] = (unsigned short)(s1 | (s2 << 4) | (u1 << 8) | (u2 << 9));
    }
    return T;
}

__constant__ Tbl TBL = make_tbl();

#define ROWS_PER_BLOCK 32
#define WORDS_PER_BLOCK (ROWS_PER_BLOCK * 495)  // 15840 words = 63360 B = 495 lines
#define UNITS 62                                // 61 full 1-KB units + 896-B tail

__global__ __launch_bounds__(256, 8) void TotalDegree_29755533426739_kernel(
    const float* __restrict__ x, float* __restrict__ out, int B) {
    __shared__ float xs[256];                    // 32-row x tile
    __shared__ float P[ROWS_PER_BLOCK * 64];     // 8 KB: P[row][0..44] (45..63 junk)
    __shared__ unsigned uvt[512];                // interleaved term->uv map

    const int tid  = (int)threadIdx.x;
    const int lane = tid & 63;
    const int wid  = tid >> 6;

    // Coalesced x-tile load: 256 threads x 4 B = 32 rows.
    {
        const int gi = (int)blockIdx.x * 256 + tid;
        xs[tid] = (gi < B * 8) ? x[gi] : 0.0f;
    }

    // P build: wave w builds rows w*8..w*8+7, reading only its own wave's xs
    // segment (written by the same wave -> no barrier needed before this).
    const int ppv  = (int)TBL.pp[lane];
    const int s1   = ppv & 15;
    const int s2   = (ppv >> 4) & 15;
    const bool use1 = ((ppv >> 8) & 1) != 0;
    const bool use2 = ((ppv >> 9) & 1) != 0;
    const float* xw = xs + wid * 64;
    #pragma unroll
    for (int rr = 0; rr < 8; ++rr) {
        const float a1 = xw[rr * 8 + s1];
        const float a2 = xw[rr * 8 + s2];
        P[(wid * 8 + rr) * 64 + lane] = (use1 ? a1 : 1.0f) * (use2 ? a2 : 1.0f);
    }
    // uv table -> LDS (2 entries per thread).
    uvt[tid] = TBL.uv4[tid];
    uvt[tid + 256] = TBL.uv4[tid + 256];
    __syncthreads();  // cross-wave P reads below

    // Flat tiling: unit s covers words [s*256, s*256+256) of the block span.
    // Lane owns words f..f+3, f = s*256 + 4*lane; row r = f/495, term t = f%495.
    float* oB = out + (unsigned)blockIdx.x * WORDS_PER_BLOCK;
    {
        const int f0 = wid * 256 + (lane << 2);  // <= 1020
        int r0 = (f0 >= 990) ? 2 : (f0 >= 495 ? 1 : 0);
        int t  = f0 - r0 * 495;
        int rb = r0 << 6;  // r*64: word offset of row r's P slice

        for (int s = wid; s < UNITS; s += 4) {
            // term->uv for t..t+3 (interleaved layout: conflict-free across lanes)
            const unsigned q0 = uvt[((t    ) & 3) * 128 + ((t    ) >> 2)];
            const unsigned q1 = uvt[((t + 1) & 3) * 128 + ((t + 1) >> 2)];
            const unsigned q2 = uvt[((t + 2) & 3) * 128 + ((t + 2) >> 2)];
            const unsigned q3 = uvt[((t + 3) & 3) * 128 + ((t + 3) >> 2)];
            // elements past a row boundary (t+k >= 495) belong to row r+1
            const int w1 = (t >= 494) ? 64 : 0;
            const int w2 = (t >= 493) ? 64 : 0;
            const int w3 = (t >= 492) ? 64 : 0;
            f32x4 v;
            v.x = P[rb      + (int)(q0 & 0xffffu)] * P[rb      + (int)(q0 >> 16)];
            v.y = P[rb + w1 + (int)(q1 & 0xffffu)] * P[rb + w1 + (int)(q1 >> 16)];
            v.z = P[rb + w2 + (int)(q2 & 0xffffu)] * P[rb + w2 + (int)(q2 >> 16)];
            v.w = P[rb + w3 + (int)(q3 & 0xffffu)] * P[rb + w3 + (int)(q3 >> 16)];
            // unit base byte = blk*63360 + s*1024: both line-multiples -> every
            // store covers whole 128-B lines. Tail unit: 224 words = 56 lanes.
            if (s < UNITS - 1 || lane < 56)
                *reinterpret_cast<f32x4*>(oB + s * 256 + (lane << 2)) = v;
            // advance 4 units = 1024 words = 2*495 + 34
            t += 34; rb += 128;
            if (t >= 495) { t -= 495; rb += 64; }
        }
    }
}

extern "C" void kernel_launch(void* const* d_in, const int* in_sizes, int n_in,
                              void* d_out, int out_size, void* d_ws, size_t ws_size,
                              hipStream_t stream) {
    const float* x = (const float*)d_in[0];
    float* out = (float*)d_out;
    const int B = in_sizes[0] / 8;  // 65536 rows
    const int grid = (B + ROWS_PER_BLOCK - 1) / ROWS_PER_BLOCK;  // 2048
    hipLaunchKernelGGL(TotalDegree_29755533426739_kernel,
                       dim3(grid), dim3(256), 0, stream, x, out, B);
}